// Round 5
// baseline (777.033 us; speedup 1.0000x reference)
//
#include <hip/hip_runtime.h>
#include <hip/hip_bf16.h>
#include <math.h>

#define CDIV(a,b) (((a)+(b)-1)/(b))

typedef __bf16  bf16x8 __attribute__((ext_vector_type(8)));
typedef float   f32x4  __attribute__((ext_vector_type(4)));
typedef unsigned short u16x8 __attribute__((ext_vector_type(8)));
typedef unsigned short u16x4 __attribute__((ext_vector_type(4)));

__device__ __forceinline__ float bf2f(unsigned short u) {
    union { unsigned int i; float f; } x; x.i = ((unsigned int)u) << 16; return x.f;
}
__device__ __forceinline__ unsigned short f2bf(float f) {
    union { float f; unsigned int i; } x; x.f = f;
    unsigned int r = x.i + 0x7fff + ((x.i >> 16) & 1);   // RNE, finite inputs
    return (unsigned short)(r >> 16);
}

// ---------------------------------------------------------------------------
// CSR build (by destination node). Edges = [E graph edges] + [n self-loops].
// ---------------------------------------------------------------------------
__global__ void hist_kernel(const int* __restrict__ ei, int* __restrict__ deg,
                            int E, int Et) {
    int e = blockIdx.x * blockDim.x + threadIdx.x;
    if (e >= Et) return;
    int d = (e < E) ? ei[E + e] : (e - E);
    atomicAdd(&deg[d], 1);
}

// Single-block exclusive scan, wave-shuffle based (4 barriers / 1024 elems).
__global__ void scan_kernel(const int* __restrict__ deg, int* __restrict__ off, int n) {
    __shared__ int wsum[16];
    __shared__ int carry_s;
    int t = threadIdx.x, lane = t & 63, wv = t >> 6;
    if (t == 0) carry_s = 0;
    __syncthreads();
    for (int base = 0; base < n; base += 1024) {
        int v = (base + t < n) ? deg[base + t] : 0;
        int x = v;
#pragma unroll
        for (int o = 1; o < 64; o <<= 1) {
            int y = __shfl_up(x, o);
            if (lane >= o) x += y;
        }
        if (lane == 63) wsum[wv] = x;
        __syncthreads();
        if (wv == 0 && lane < 16) {
            int s = wsum[lane];
#pragma unroll
            for (int o = 1; o < 16; o <<= 1) {
                int y = __shfl_up(s, o);
                if (lane >= o) s += y;
            }
            wsum[lane] = s;
        }
        __syncthreads();
        int wprev = (wv == 0) ? 0 : wsum[wv - 1];
        int incl = carry_s + wprev + x;
        if (base + t < n) off[base + t] = incl - v;
        __syncthreads();
        if (t == 1023) carry_s = incl;
        __syncthreads();
    }
    if (t == 0) off[n] = carry_s;
}

__global__ void scatter_kernel(const int* __restrict__ ei, const int* __restrict__ off,
                               int* __restrict__ cur, int* __restrict__ csr,
                               int E, int Et) {
    int e = blockIdx.x * blockDim.x + threadIdx.x;
    if (e >= Et) return;
    int s, d;
    if (e < E) { s = ei[e]; d = ei[E + e]; } else { s = e - E; d = s; }
    int pos = off[d] + atomicAdd(&cur[d], 1);
    csr[pos] = s;
}

// ---------------------------------------------------------------------------
// Weight transpose + fp32 -> bf16:  wt[N,K] <- w[K,N]
// ---------------------------------------------------------------------------
__global__ void wt_transpose_kernel(const float* __restrict__ w,
                                    __hip_bfloat16* __restrict__ wt,
                                    int K, int N) {
    __shared__ float tile[32][33];
    int kb = blockIdx.x * 32, nb = blockIdx.y * 32;
    int tx = threadIdx.x & 31, ty = threadIdx.x >> 5;   // 256 threads
    for (int i = ty; i < 32; i += 8)
        tile[i][tx] = w[(size_t)(kb + i) * N + nb + tx];
    __syncthreads();
    for (int i = ty; i < 32; i += 8)
        wt[(size_t)(nb + i) * K + kb + tx] = __float2bfloat16(tile[tx][i]);
}

__global__ void cvt_bf16_kernel(const float* __restrict__ in,
                                __hip_bfloat16* __restrict__ out, int total) {
    int i = blockIdx.x * blockDim.x + threadIdx.x;
    if (i < total) out[i] = __float2bfloat16(in[i]);
}

// b_eff[j] = sum_k proj_b[k] * w1[k][j]   (fp32, coalesced over j)
__global__ void beff_kernel(const float* __restrict__ pb, const float* __restrict__ w1,
                            float* __restrict__ beff, int K, int N) {
    int j = blockIdx.x * blockDim.x + threadIdx.x;
    if (j >= N) return;
    float s = 0.f;
    for (int k = 0; k < K; k++) s = fmaf(pb[k], w1[(size_t)k * N + j], s);
    beff[j] = s;
}

// ---------------------------------------------------------------------------
// bf16 MFMA GEMM: Cb[M,N] = bf16(A[M,K] @ BT[N,K]^T (+bias))
// 128x128 tile, BK=32, 256 threads (4 waves), 16x16x32 MFMA.
// XCD-aware 1-D swizzle: xcd = bid&7 owns a contiguous x-stripe of XT M-tiles,
// slots x-outer/y-inner so A-tile consumers are consecutive on ONE XCD.
// ---------------------------------------------------------------------------
__device__ __forceinline__ void gload16(void* lds, const void* g) {
    __builtin_amdgcn_global_load_lds(
        (const __attribute__((address_space(1))) void*)g,
        (__attribute__((address_space(3))) void*)lds, 16, 0, 0);
}

__global__ __launch_bounds__(256) void gemm_bf16_kernel(
    const __hip_bfloat16* __restrict__ A,
    const __hip_bfloat16* __restrict__ BT,
    const float* __restrict__ bias,
    __hip_bfloat16* __restrict__ Cb,
    int M, int N, int K, int MB, int NB, int XT)
{
    __shared__ __align__(16) __hip_bfloat16 As[128 * 32];
    __shared__ __align__(16) __hip_bfloat16 Bs[128 * 32];

    const int bid  = blockIdx.x;
    const int xcd  = bid & 7;
    const int slot = bid >> 3;
    const int x_sub = slot / NB;
    const int yb    = slot - x_sub * NB;
    const int xb    = xcd * XT + x_sub;
    if (xb >= MB) return;

    const int tid = threadIdx.x;
    const int m0 = xb * 128, n0 = yb * 128;
    const int w = tid >> 6, l = tid & 63;
    const int wm = (w & 1) * 64, wn = (w >> 1) * 64;
    const int lm = l & 15, lq = l >> 4;

    f32x4 acc[4][4] = {};

    const int arow = tid >> 2;          // 0..63
    const int acol = (tid & 3) * 8;     // bf16 elems within 32-wide k slab
    const __hip_bfloat16* Ag = A  + (size_t)(m0 + arow) * K + acol;
    const __hip_bfloat16* Bg = BT + (size_t)(n0 + arow) * K + acol;
    char* AsW = (char*)As + (w << 10);  // wave-uniform LDS base
    char* BsW = (char*)Bs + (w << 10);

    for (int k0 = 0; k0 < K; k0 += 32) {
        gload16(AsW,        Ag + k0);
        gload16(AsW + 4096, Ag + (size_t)64 * K + k0);
        gload16(BsW,        Bg + k0);
        gload16(BsW + 4096, Bg + (size_t)64 * K + k0);
        __syncthreads();
        bf16x8 af[4], bfr[4];
#pragma unroll
        for (int i = 0; i < 4; i++)
            af[i] = *(const bf16x8*)(As + (wm + i * 16 + lm) * 32 + lq * 8);
#pragma unroll
        for (int j = 0; j < 4; j++)
            bfr[j] = *(const bf16x8*)(Bs + (wn + j * 16 + lm) * 32 + lq * 8);
#pragma unroll
        for (int i = 0; i < 4; i++)
#pragma unroll
            for (int j = 0; j < 4; j++)
                acc[i][j] = __builtin_amdgcn_mfma_f32_16x16x32_bf16(
                    af[i], bfr[j], acc[i][j], 0, 0, 0);
        __syncthreads();
    }

#pragma unroll
    for (int i = 0; i < 4; i++) {
        int rb = m0 + wm + i * 16 + lq * 4;
#pragma unroll
        for (int r = 0; r < 4; r++) {
            int row = rb + r;
            if (row >= M) continue;
#pragma unroll
            for (int j = 0; j < 4; j++) {
                int col = n0 + wn + j * 16 + lm;
                float v = acc[i][j][r];
                if (bias) v += bias[col];
                Cb[(size_t)row * N + col] = __float2bfloat16(v);
            }
        }
    }
}

// ---------------------------------------------------------------------------
// es/ed: per-node per-head dot with a_src/a_dst (h in bf16). One wave/head.
// ---------------------------------------------------------------------------
__global__ void esed_kernel(const __hip_bfloat16* __restrict__ h,
                            const float* __restrict__ a_src,
                            const float* __restrict__ a_dst,
                            float* __restrict__ es, float* __restrict__ ed, int H) {
    int nidx = blockIdx.x;
    int t = threadIdx.x;
    int head = t >> 6, lane = t & 63;
    const unsigned short* hp =
        (const unsigned short*)h + (size_t)nidx * H * 512 + head * 512 + lane * 8;
    const float* sp = a_src + head * 512 + lane * 8;
    const float* dp = a_dst + head * 512 + lane * 8;
    u16x8 hv = *(const u16x8*)hp;
    float4 s0 = *(const float4*)sp, s1 = *(const float4*)(sp + 4);
    float4 d0 = *(const float4*)dp, d1 = *(const float4*)(dp + 4);
    float hf[8];
#pragma unroll
    for (int k = 0; k < 8; k++) hf[k] = bf2f(hv[k]);
    float s = hf[0]*s0.x + hf[1]*s0.y + hf[2]*s0.z + hf[3]*s0.w
            + hf[4]*s1.x + hf[5]*s1.y + hf[6]*s1.z + hf[7]*s1.w;
    float d = hf[0]*d0.x + hf[1]*d0.y + hf[2]*d0.z + hf[3]*d0.w
            + hf[4]*d1.x + hf[5]*d1.y + hf[6]*d1.z + hf[7]*d1.w;
    for (int o = 32; o; o >>= 1) { s += __shfl_down(s, o); d += __shfl_down(d, o); }
    if (lane == 0) { es[nidx * H + head] = s; ed[nidx * H + head] = d; }
}

// ---------------------------------------------------------------------------
// Aggregation: ONE block per dst, all heads. Thread t owns channels
// [t*VEC, t*VEC+VEC). 4x edge unroll for memory-level parallelism.
// MEAN variant (layer 3) fuses head-mean + bias -> fp32 out.
// ---------------------------------------------------------------------------
template<int H, int VEC, bool MEAN>
__global__ __launch_bounds__(256) void agg_kernel(
    const __hip_bfloat16* __restrict__ h, const float* __restrict__ es,
    const float* __restrict__ ed, const int* __restrict__ csr,
    const int* __restrict__ off, const float* __restrict__ bias,
    float* __restrict__ outF, __hip_bfloat16* __restrict__ outB, int do_elu)
{
    constexpr int HS = H * 512;
    __shared__ float red[MEAN ? 1024 : 1];
    int d = blockIdx.x, t = threadIdx.x;
    int c0 = t * VEC;
    int head = c0 >> 9;                       // wave-uniform
    float edd = ed[d * H + head];
    int beg = off[d], end = off[d + 1];
    float acc[VEC];
#pragma unroll
    for (int k = 0; k < VEC; k++) acc[k] = 0.f;
    float den = 0.f;
    const unsigned short* hb = (const unsigned short*)h;

    int i = beg;
    for (; i + 3 < end; i += 4) {
        int   s[4];
        float wgt[4];
#pragma unroll
        for (int u = 0; u < 4; u++) {
            s[u] = csr[i + u];
            float e = es[s[u] * H + head] + edd;
            e = (e > 0.f) ? e : 0.2f * e;
            wgt[u] = __expf(e);
        }
        if constexpr (VEC == 8) {
            u16x8 v[4];
#pragma unroll
            for (int u = 0; u < 4; u++)
                v[u] = *(const u16x8*)(hb + (size_t)s[u] * HS + c0);
#pragma unroll
            for (int u = 0; u < 4; u++) {
                den += wgt[u];
#pragma unroll
                for (int k = 0; k < 8; k++) acc[k] = fmaf(wgt[u], bf2f(v[u][k]), acc[k]);
            }
        } else {
            u16x4 v[4];
#pragma unroll
            for (int u = 0; u < 4; u++)
                v[u] = *(const u16x4*)(hb + (size_t)s[u] * HS + c0);
#pragma unroll
            for (int u = 0; u < 4; u++) {
                den += wgt[u];
#pragma unroll
                for (int k = 0; k < VEC; k++) acc[k] = fmaf(wgt[u], bf2f(v[u][k]), acc[k]);
            }
        }
    }
    for (; i < end; i++) {
        int s0 = csr[i];
        float e0 = es[s0 * H + head] + edd;
        e0 = (e0 > 0.f) ? e0 : 0.2f * e0;
        float w0 = __expf(e0);
        den += w0;
        const unsigned short* hp0 = hb + (size_t)s0 * HS + c0;
        if constexpr (VEC == 8) {
            u16x8 v0 = *(const u16x8*)hp0;
#pragma unroll
            for (int k = 0; k < 8; k++) acc[k] = fmaf(w0, bf2f(v0[k]), acc[k]);
        } else {
            u16x4 v0 = *(const u16x4*)hp0;
#pragma unroll
            for (int k = 0; k < VEC; k++) acc[k] = fmaf(w0, bf2f(v0[k]), acc[k]);
        }
    }

    float inv = 1.f / den;
    if constexpr (!MEAN) {
        u16x8 ov;
#pragma unroll
        for (int k = 0; k < VEC; k++) {
            float v = acc[k] * inv + bias[c0 + k];
            if (do_elu) v = (v > 0.f) ? v : expm1f(v);
            ov[k] = f2bf(v);
        }
        *(u16x8*)((unsigned short*)outB + (size_t)d * HS + c0) = ov;
    } else {
#pragma unroll
        for (int k = 0; k < VEC; k++) red[c0 + k] = acc[k] * inv;
        __syncthreads();
        if (t < 128) {
#pragma unroll
            for (int k = 0; k < 4; k++) {
                int c = t * 4 + k;
                outF[(size_t)d * 512 + c] = 0.5f * (red[c] + red[c + 512]) + bias[c];
            }
        }
    }
}

// ---------------------------------------------------------------------------
extern "C" void kernel_launch(void* const* d_in, const int* in_sizes, int n_in,
                              void* d_out, int out_size, void* d_ws, size_t ws_size,
                              hipStream_t stream) {
    const float* x      = (const float*)d_in[0];
    const int*   ei     = (const int*)  d_in[1];
    const float* proj_w = (const float*)d_in[2];
    const float* proj_b = (const float*)d_in[3];
    const float* w1  = (const float*)d_in[4];
    const float* as1 = (const float*)d_in[5];
    const float* ad1 = (const float*)d_in[6];
    const float* b1  = (const float*)d_in[7];
    const float* w2  = (const float*)d_in[8];
    const float* as2 = (const float*)d_in[9];
    const float* ad2 = (const float*)d_in[10];
    const float* b2  = (const float*)d_in[11];
    const float* w3  = (const float*)d_in[12];
    const float* as3 = (const float*)d_in[13];
    const float* ad3 = (const float*)d_in[14];
    const float* b3  = (const float*)d_in[15];

    const int n    = in_sizes[0] / 256;   // 10000
    const int E    = in_sizes[1] / 2;     // 160000
    const int Et   = E + n;               // 170000
    const int MB   = CDIV(n, 128);        // 79
    const int Mpad = MB * 128;            // 10112
    const int XT   = CDIV(MB, 8);         // 10 M-tiles per XCD stripe

    char* p = (char*)d_ws;
    auto carve = [&](size_t bytes) {
        void* r = (void*)p;
        p += (bytes + 255) & ~(size_t)255;
        return r;
    };
    __hip_bfloat16* h_bf    = (__hip_bfloat16*)carve((size_t)Mpad * 2048 * sizeof(__hip_bfloat16));
    __hip_bfloat16* act_bf  = (__hip_bfloat16*)carve((size_t)Mpad * 2048 * sizeof(__hip_bfloat16));
    __hip_bfloat16* x_bf    = (__hip_bfloat16*)carve((size_t)Mpad * 256 * sizeof(__hip_bfloat16));
    __hip_bfloat16* pw_bf   = (__hip_bfloat16*)carve((size_t)256 * 512 * sizeof(__hip_bfloat16));
    __hip_bfloat16* w1t     = (__hip_bfloat16*)carve((size_t)2048 * 512 * sizeof(__hip_bfloat16));
    __hip_bfloat16* w2t     = (__hip_bfloat16*)carve((size_t)2048 * 2048 * sizeof(__hip_bfloat16));
    __hip_bfloat16* w3t     = (__hip_bfloat16*)carve((size_t)1024 * 2048 * sizeof(__hip_bfloat16));
    __hip_bfloat16* w_efft  = (__hip_bfloat16*)carve((size_t)2048 * 256 * sizeof(__hip_bfloat16));
    float* b_eff = (float*)carve((size_t)2048 * sizeof(float));
    float* es  = (float*)carve((size_t)n * 4 * sizeof(float));
    float* ed  = (float*)carve((size_t)n * 4 * sizeof(float));
    int* deg = (int*)carve((size_t)n * sizeof(int));
    int* cur = (int*)carve((size_t)n * sizeof(int));
    int* off = (int*)carve((size_t)(n + 1) * sizeof(int));
    int* csr = (int*)carve((size_t)Et * sizeof(int));
    (void)ws_size; (void)n_in;

    // --- CSR build ---
    hipMemsetAsync(deg, 0, n * sizeof(int), stream);
    hipMemsetAsync(cur, 0, n * sizeof(int), stream);
    hist_kernel<<<CDIV(Et, 256), 256, 0, stream>>>(ei, deg, E, Et);
    scan_kernel<<<1, 1024, 0, stream>>>(deg, off, n);
    scatter_kernel<<<CDIV(Et, 256), 256, 0, stream>>>(ei, off, cur, csr, E, Et);

    // --- weight prep ---
    wt_transpose_kernel<<<dim3(512 / 32, 2048 / 32), 256, 0, stream>>>(w1, w1t, 512, 2048);
    wt_transpose_kernel<<<dim3(2048 / 32, 2048 / 32),256, 0, stream>>>(w2, w2t, 2048, 2048);
    wt_transpose_kernel<<<dim3(2048 / 32, 1024 / 32),256, 0, stream>>>(w3, w3t, 2048, 1024);
    cvt_bf16_kernel<<<CDIV(256 * 512, 256), 256, 0, stream>>>(proj_w, pw_bf, 256 * 512);
    cvt_bf16_kernel<<<CDIV(n * 256, 256), 256, 0, stream>>>(x, x_bf, n * 256);

    // --- fold proj into layer 1: W_eff^T[2048,256] = w1t[2048,512] @ pw_bf[256,512]^T
    //     (w_efft[m][i] = sum_k w1[k][m] * proj_w[i][k]);  b_eff = proj_b @ w1
    gemm_bf16_kernel<<<8 * 2 * 2, 256, 0, stream>>>(
        w1t, pw_bf, nullptr, w_efft, 2048, 256, 512, 16, 2, 2);
    beff_kernel<<<CDIV(2048, 256), 256, 0, stream>>>(proj_b, w1, b_eff, 512, 2048);

    auto gemm_grid = [&](int NB) { return 8 * XT * NB; };

    // --- layer 1 (H=4, concat, ELU):  h = x @ W_eff + b_eff ---
    gemm_bf16_kernel<<<gemm_grid(16), 256, 0, stream>>>(
        x_bf, w_efft, b_eff, h_bf, n, 2048, 256, MB, 16, XT);
    esed_kernel<<<n, 4 * 64, 0, stream>>>(h_bf, as1, ad1, es, ed, 4);
    agg_kernel<4, 8, false><<<n, 256, 0, stream>>>(h_bf, es, ed, csr, off, b1,
                                                   nullptr, act_bf, 1);

    // --- layer 2 (H=4, concat, ELU) ---
    gemm_bf16_kernel<<<gemm_grid(16), 256, 0, stream>>>(
        act_bf, w2t, nullptr, h_bf, n, 2048, 2048, MB, 16, XT);
    esed_kernel<<<n, 4 * 64, 0, stream>>>(h_bf, as2, ad2, es, ed, 4);
    agg_kernel<4, 8, false><<<n, 256, 0, stream>>>(h_bf, es, ed, csr, off, b2,
                                                   nullptr, act_bf, 1);

    // --- layer 3 (H=2, mean+bias fused, no ELU) ---
    gemm_bf16_kernel<<<gemm_grid(8), 256, 0, stream>>>(
        act_bf, w3t, nullptr, h_bf, n, 1024, 2048, MB, 8, XT);
    esed_kernel<<<n, 2 * 64, 0, stream>>>(h_bf, as3, ad3, es, ed, 2);
    agg_kernel<2, 4, true><<<n, 256, 0, stream>>>(h_bf, es, ed, csr, off, b3,
                                                  (float*)d_out, nullptr, 0);
}

// Round 6
// 674.417 us; speedup vs baseline: 1.1522x; 1.1522x over previous
//
#include <hip/hip_runtime.h>
#include <hip/hip_bf16.h>
#include <math.h>

#define CDIV(a,b) (((a)+(b)-1)/(b))

typedef __bf16  bf16x8 __attribute__((ext_vector_type(8)));
typedef float   f32x4  __attribute__((ext_vector_type(4)));
typedef unsigned short u16x8 __attribute__((ext_vector_type(8)));
typedef unsigned short u16x4 __attribute__((ext_vector_type(4)));

__device__ __forceinline__ float bf2f(unsigned short u) {
    union { unsigned int i; float f; } x; x.i = ((unsigned int)u) << 16; return x.f;
}
__device__ __forceinline__ unsigned short f2bf(float f) {
    union { float f; unsigned int i; } x; x.f = f;
    unsigned int r = x.i + 0x7fff + ((x.i >> 16) & 1);   // RNE, finite inputs
    return (unsigned short)(r >> 16);
}

// ---------------------------------------------------------------------------
// CSR build (by destination node). Edges = [E graph edges] + [n self-loops].
// ---------------------------------------------------------------------------
__global__ void hist_kernel(const int* __restrict__ ei, int* __restrict__ deg,
                            int E, int Et) {
    int e = blockIdx.x * blockDim.x + threadIdx.x;
    if (e >= Et) return;
    int d = (e < E) ? ei[E + e] : (e - E);
    atomicAdd(&deg[d], 1);
}

// Single-block exclusive scan, wave-shuffle based (4 barriers / 1024 elems).
__global__ void scan_kernel(const int* __restrict__ deg, int* __restrict__ off, int n) {
    __shared__ int wsum[16];
    __shared__ int carry_s;
    int t = threadIdx.x, lane = t & 63, wv = t >> 6;
    if (t == 0) carry_s = 0;
    __syncthreads();
    for (int base = 0; base < n; base += 1024) {
        int v = (base + t < n) ? deg[base + t] : 0;
        int x = v;
#pragma unroll
        for (int o = 1; o < 64; o <<= 1) {
            int y = __shfl_up(x, o);
            if (lane >= o) x += y;
        }
        if (lane == 63) wsum[wv] = x;
        __syncthreads();
        if (wv == 0 && lane < 16) {
            int s = wsum[lane];
#pragma unroll
            for (int o = 1; o < 16; o <<= 1) {
                int y = __shfl_up(s, o);
                if (lane >= o) s += y;
            }
            wsum[lane] = s;
        }
        __syncthreads();
        int wprev = (wv == 0) ? 0 : wsum[wv - 1];
        int incl = carry_s + wprev + x;
        if (base + t < n) off[base + t] = incl - v;
        __syncthreads();
        if (t == 1023) carry_s = incl;
        __syncthreads();
    }
    if (t == 0) off[n] = carry_s;
}

__global__ void scatter_kernel(const int* __restrict__ ei, const int* __restrict__ off,
                               int* __restrict__ cur, int* __restrict__ csr,
                               int E, int Et) {
    int e = blockIdx.x * blockDim.x + threadIdx.x;
    if (e >= Et) return;
    int s, d;
    if (e < E) { s = ei[e]; d = ei[E + e]; } else { s = e - E; d = s; }
    int pos = off[d] + atomicAdd(&cur[d], 1);
    csr[pos] = s;
}

// ---------------------------------------------------------------------------
// Weight transpose + fp32 -> bf16:  wt[N,K] <- w[K,N]
// ---------------------------------------------------------------------------
__global__ void wt_transpose_kernel(const float* __restrict__ w,
                                    __hip_bfloat16* __restrict__ wt,
                                    int K, int N) {
    __shared__ float tile[32][33];
    int kb = blockIdx.x * 32, nb = blockIdx.y * 32;
    int tx = threadIdx.x & 31, ty = threadIdx.x >> 5;   // 256 threads
    for (int i = ty; i < 32; i += 8)
        tile[i][tx] = w[(size_t)(kb + i) * N + nb + tx];
    __syncthreads();
    for (int i = ty; i < 32; i += 8)
        wt[(size_t)(nb + i) * K + kb + tx] = __float2bfloat16(tile[tx][i]);
}

__global__ void cvt_bf16_kernel(const float* __restrict__ in,
                                __hip_bfloat16* __restrict__ out, int total) {
    int i = blockIdx.x * blockDim.x + threadIdx.x;
    if (i < total) out[i] = __float2bfloat16(in[i]);
}

// b_eff[j] += sum over this block's k-chunk of proj_b[k]*w1[k][j].
// k-split across blockIdx.y (64 ks, fully unrolled -> 64 outstanding loads),
// j across blockIdx.x*256+t (coalesced). b_eff must be zeroed first.
__global__ void beff_kernel(const float* __restrict__ pb, const float* __restrict__ w1,
                            float* __restrict__ beff, int N) {
    int j  = blockIdx.x * 256 + threadIdx.x;
    int k0 = blockIdx.y * 64;
    float s = 0.f;
#pragma unroll
    for (int k = 0; k < 64; k++)
        s = fmaf(pb[k0 + k], w1[(size_t)(k0 + k) * N + j], s);
    atomicAdd(&beff[j], s);
}

// ---------------------------------------------------------------------------
// bf16 MFMA GEMM: Cb[M,N] = bf16(A[M,K] @ BT[N,K]^T (+bias))
// 128x128 tile, BK=32, 256 threads (4 waves), 16x16x32 MFMA.
// XCD-aware 1-D swizzle: xcd = bid&7 owns a contiguous x-stripe of XT M-tiles,
// slots x-outer/y-inner so A-tile consumers are consecutive on ONE XCD.
// ---------------------------------------------------------------------------
__device__ __forceinline__ void gload16(void* lds, const void* g) {
    __builtin_amdgcn_global_load_lds(
        (const __attribute__((address_space(1))) void*)g,
        (__attribute__((address_space(3))) void*)lds, 16, 0, 0);
}

__global__ __launch_bounds__(256) void gemm_bf16_kernel(
    const __hip_bfloat16* __restrict__ A,
    const __hip_bfloat16* __restrict__ BT,
    const float* __restrict__ bias,
    __hip_bfloat16* __restrict__ Cb,
    int M, int N, int K, int MB, int NB, int XT)
{
    __shared__ __align__(16) __hip_bfloat16 As[128 * 32];
    __shared__ __align__(16) __hip_bfloat16 Bs[128 * 32];

    const int bid  = blockIdx.x;
    const int xcd  = bid & 7;
    const int slot = bid >> 3;
    const int x_sub = slot / NB;
    const int yb    = slot - x_sub * NB;
    const int xb    = xcd * XT + x_sub;
    if (xb >= MB) return;

    const int tid = threadIdx.x;
    const int m0 = xb * 128, n0 = yb * 128;
    const int w = tid >> 6, l = tid & 63;
    const int wm = (w & 1) * 64, wn = (w >> 1) * 64;
    const int lm = l & 15, lq = l >> 4;

    f32x4 acc[4][4] = {};

    const int arow = tid >> 2;          // 0..63
    const int acol = (tid & 3) * 8;     // bf16 elems within 32-wide k slab
    const __hip_bfloat16* Ag = A  + (size_t)(m0 + arow) * K + acol;
    const __hip_bfloat16* Bg = BT + (size_t)(n0 + arow) * K + acol;
    char* AsW = (char*)As + (w << 10);  // wave-uniform LDS base
    char* BsW = (char*)Bs + (w << 10);

    for (int k0 = 0; k0 < K; k0 += 32) {
        gload16(AsW,        Ag + k0);
        gload16(AsW + 4096, Ag + (size_t)64 * K + k0);
        gload16(BsW,        Bg + k0);
        gload16(BsW + 4096, Bg + (size_t)64 * K + k0);
        __syncthreads();
        bf16x8 af[4], bfr[4];
#pragma unroll
        for (int i = 0; i < 4; i++)
            af[i] = *(const bf16x8*)(As + (wm + i * 16 + lm) * 32 + lq * 8);
#pragma unroll
        for (int j = 0; j < 4; j++)
            bfr[j] = *(const bf16x8*)(Bs + (wn + j * 16 + lm) * 32 + lq * 8);
#pragma unroll
        for (int i = 0; i < 4; i++)
#pragma unroll
            for (int j = 0; j < 4; j++)
                acc[i][j] = __builtin_amdgcn_mfma_f32_16x16x32_bf16(
                    af[i], bfr[j], acc[i][j], 0, 0, 0);
        __syncthreads();
    }

#pragma unroll
    for (int i = 0; i < 4; i++) {
        int rb = m0 + wm + i * 16 + lq * 4;
#pragma unroll
        for (int r = 0; r < 4; r++) {
            int row = rb + r;
            if (row >= M) continue;
#pragma unroll
            for (int j = 0; j < 4; j++) {
                int col = n0 + wn + j * 16 + lm;
                float v = acc[i][j][r];
                if (bias) v += bias[col];
                Cb[(size_t)row * N + col] = __float2bfloat16(v);
            }
        }
    }
}

// ---------------------------------------------------------------------------
// es/ed: per-node per-head dot with a_src/a_dst (h in bf16). One wave/head.
// ---------------------------------------------------------------------------
__global__ void esed_kernel(const __hip_bfloat16* __restrict__ h,
                            const float* __restrict__ a_src,
                            const float* __restrict__ a_dst,
                            float* __restrict__ es, float* __restrict__ ed, int H) {
    int nidx = blockIdx.x;
    int t = threadIdx.x;
    int head = t >> 6, lane = t & 63;
    const unsigned short* hp =
        (const unsigned short*)h + (size_t)nidx * H * 512 + head * 512 + lane * 8;
    const float* sp = a_src + head * 512 + lane * 8;
    const float* dp = a_dst + head * 512 + lane * 8;
    u16x8 hv = *(const u16x8*)hp;
    float4 s0 = *(const float4*)sp, s1 = *(const float4*)(sp + 4);
    float4 d0 = *(const float4*)dp, d1 = *(const float4*)(dp + 4);
    float hf[8];
#pragma unroll
    for (int k = 0; k < 8; k++) hf[k] = bf2f(hv[k]);
    float s = hf[0]*s0.x + hf[1]*s0.y + hf[2]*s0.z + hf[3]*s0.w
            + hf[4]*s1.x + hf[5]*s1.y + hf[6]*s1.z + hf[7]*s1.w;
    float d = hf[0]*d0.x + hf[1]*d0.y + hf[2]*d0.z + hf[3]*d0.w
            + hf[4]*d1.x + hf[5]*d1.y + hf[6]*d1.z + hf[7]*d1.w;
    for (int o = 32; o; o >>= 1) { s += __shfl_down(s, o); d += __shfl_down(d, o); }
    if (lane == 0) { es[nidx * H + head] = s; ed[nidx * H + head] = d; }
}

// ---------------------------------------------------------------------------
// Aggregation: ONE block per dst, all heads. Thread t owns channels
// [t*VEC, t*VEC+VEC). 4x edge unroll for memory-level parallelism.
// MEAN variant (layer 3) fuses head-mean + bias -> fp32 out.
// ---------------------------------------------------------------------------
template<int H, int VEC, bool MEAN>
__global__ __launch_bounds__(256) void agg_kernel(
    const __hip_bfloat16* __restrict__ h, const float* __restrict__ es,
    const float* __restrict__ ed, const int* __restrict__ csr,
    const int* __restrict__ off, const float* __restrict__ bias,
    float* __restrict__ outF, __hip_bfloat16* __restrict__ outB, int do_elu)
{
    constexpr int HS = H * 512;
    __shared__ float red[MEAN ? 1024 : 1];
    int d = blockIdx.x, t = threadIdx.x;
    int c0 = t * VEC;
    int head = c0 >> 9;                       // wave-uniform
    float edd = ed[d * H + head];
    int beg = off[d], end = off[d + 1];
    float acc[VEC];
#pragma unroll
    for (int k = 0; k < VEC; k++) acc[k] = 0.f;
    float den = 0.f;
    const unsigned short* hb = (const unsigned short*)h;

    int i = beg;
    for (; i + 3 < end; i += 4) {
        int   s[4];
        float wgt[4];
#pragma unroll
        for (int u = 0; u < 4; u++) {
            s[u] = csr[i + u];
            float e = es[s[u] * H + head] + edd;
            e = (e > 0.f) ? e : 0.2f * e;
            wgt[u] = __expf(e);
        }
        if constexpr (VEC == 8) {
            u16x8 v[4];
#pragma unroll
            for (int u = 0; u < 4; u++)
                v[u] = *(const u16x8*)(hb + (size_t)s[u] * HS + c0);
#pragma unroll
            for (int u = 0; u < 4; u++) {
                den += wgt[u];
#pragma unroll
                for (int k = 0; k < 8; k++) acc[k] = fmaf(wgt[u], bf2f(v[u][k]), acc[k]);
            }
        } else {
            u16x4 v[4];
#pragma unroll
            for (int u = 0; u < 4; u++)
                v[u] = *(const u16x4*)(hb + (size_t)s[u] * HS + c0);
#pragma unroll
            for (int u = 0; u < 4; u++) {
                den += wgt[u];
#pragma unroll
                for (int k = 0; k < VEC; k++) acc[k] = fmaf(wgt[u], bf2f(v[u][k]), acc[k]);
            }
        }
    }
    for (; i < end; i++) {
        int s0 = csr[i];
        float e0 = es[s0 * H + head] + edd;
        e0 = (e0 > 0.f) ? e0 : 0.2f * e0;
        float w0 = __expf(e0);
        den += w0;
        const unsigned short* hp0 = hb + (size_t)s0 * HS + c0;
        if constexpr (VEC == 8) {
            u16x8 v0 = *(const u16x8*)hp0;
#pragma unroll
            for (int k = 0; k < 8; k++) acc[k] = fmaf(w0, bf2f(v0[k]), acc[k]);
        } else {
            u16x4 v0 = *(const u16x4*)hp0;
#pragma unroll
            for (int k = 0; k < VEC; k++) acc[k] = fmaf(w0, bf2f(v0[k]), acc[k]);
        }
    }

    float inv = 1.f / den;
    if constexpr (!MEAN) {
        u16x8 ov;
#pragma unroll
        for (int k = 0; k < VEC; k++) {
            float v = acc[k] * inv + bias[c0 + k];
            if (do_elu) v = (v > 0.f) ? v : expm1f(v);
            ov[k] = f2bf(v);
        }
        *(u16x8*)((unsigned short*)outB + (size_t)d * HS + c0) = ov;
    } else {
#pragma unroll
        for (int k = 0; k < VEC; k++) red[c0 + k] = acc[k] * inv;
        __syncthreads();
        if (t < 128) {
#pragma unroll
            for (int k = 0; k < 4; k++) {
                int c = t * 4 + k;
                outF[(size_t)d * 512 + c] = 0.5f * (red[c] + red[c + 512]) + bias[c];
            }
        }
    }
}

// ---------------------------------------------------------------------------
extern "C" void kernel_launch(void* const* d_in, const int* in_sizes, int n_in,
                              void* d_out, int out_size, void* d_ws, size_t ws_size,
                              hipStream_t stream) {
    const float* x      = (const float*)d_in[0];
    const int*   ei     = (const int*)  d_in[1];
    const float* proj_w = (const float*)d_in[2];
    const float* proj_b = (const float*)d_in[3];
    const float* w1  = (const float*)d_in[4];
    const float* as1 = (const float*)d_in[5];
    const float* ad1 = (const float*)d_in[6];
    const float* b1  = (const float*)d_in[7];
    const float* w2  = (const float*)d_in[8];
    const float* as2 = (const float*)d_in[9];
    const float* ad2 = (const float*)d_in[10];
    const float* b2  = (const float*)d_in[11];
    const float* w3  = (const float*)d_in[12];
    const float* as3 = (const float*)d_in[13];
    const float* ad3 = (const float*)d_in[14];
    const float* b3  = (const float*)d_in[15];

    const int n    = in_sizes[0] / 256;   // 10000
    const int E    = in_sizes[1] / 2;     // 160000
    const int Et   = E + n;               // 170000
    const int MB   = CDIV(n, 128);        // 79
    const int Mpad = MB * 128;            // 10112
    const int XT   = CDIV(MB, 8);         // 10 M-tiles per XCD stripe

    char* p = (char*)d_ws;
    auto carve = [&](size_t bytes) {
        void* r = (void*)p;
        p += (bytes + 255) & ~(size_t)255;
        return r;
    };
    __hip_bfloat16* h_bf    = (__hip_bfloat16*)carve((size_t)Mpad * 2048 * sizeof(__hip_bfloat16));
    __hip_bfloat16* act_bf  = (__hip_bfloat16*)carve((size_t)Mpad * 2048 * sizeof(__hip_bfloat16));
    __hip_bfloat16* x_bf    = (__hip_bfloat16*)carve((size_t)Mpad * 256 * sizeof(__hip_bfloat16));
    __hip_bfloat16* pw_bf   = (__hip_bfloat16*)carve((size_t)256 * 512 * sizeof(__hip_bfloat16));
    __hip_bfloat16* w1t     = (__hip_bfloat16*)carve((size_t)2048 * 512 * sizeof(__hip_bfloat16));
    __hip_bfloat16* w2t     = (__hip_bfloat16*)carve((size_t)2048 * 2048 * sizeof(__hip_bfloat16));
    __hip_bfloat16* w3t     = (__hip_bfloat16*)carve((size_t)1024 * 2048 * sizeof(__hip_bfloat16));
    __hip_bfloat16* w_efft  = (__hip_bfloat16*)carve((size_t)2048 * 256 * sizeof(__hip_bfloat16));
    float* b_eff = (float*)carve((size_t)2048 * sizeof(float));
    float* es  = (float*)carve((size_t)n * 4 * sizeof(float));
    float* ed  = (float*)carve((size_t)n * 4 * sizeof(float));
    int* deg = (int*)carve((size_t)n * sizeof(int));
    int* cur = (int*)carve((size_t)n * sizeof(int));
    int* off = (int*)carve((size_t)(n + 1) * sizeof(int));
    int* csr = (int*)carve((size_t)Et * sizeof(int));
    (void)ws_size; (void)n_in;

    // --- CSR build ---
    hipMemsetAsync(deg, 0, n * sizeof(int), stream);
    hipMemsetAsync(cur, 0, n * sizeof(int), stream);
    hipMemsetAsync(b_eff, 0, 2048 * sizeof(float), stream);
    hist_kernel<<<CDIV(Et, 256), 256, 0, stream>>>(ei, deg, E, Et);
    scan_kernel<<<1, 1024, 0, stream>>>(deg, off, n);
    scatter_kernel<<<CDIV(Et, 256), 256, 0, stream>>>(ei, off, cur, csr, E, Et);

    // --- weight prep ---
    wt_transpose_kernel<<<dim3(512 / 32, 2048 / 32), 256, 0, stream>>>(w1, w1t, 512, 2048);
    wt_transpose_kernel<<<dim3(2048 / 32, 2048 / 32),256, 0, stream>>>(w2, w2t, 2048, 2048);
    wt_transpose_kernel<<<dim3(2048 / 32, 1024 / 32),256, 0, stream>>>(w3, w3t, 2048, 1024);
    cvt_bf16_kernel<<<CDIV(256 * 512, 256), 256, 0, stream>>>(proj_w, pw_bf, 256 * 512);
    cvt_bf16_kernel<<<CDIV(n * 256, 256), 256, 0, stream>>>(x, x_bf, n * 256);

    // --- fold proj into layer 1: W_eff^T[2048,256] = w1t[2048,512] @ pw_bf[256,512]^T
    //     (w_efft[m][i] = sum_k w1[k][m] * proj_w[i][k]);  b_eff = proj_b @ w1
    gemm_bf16_kernel<<<8 * 2 * 2, 256, 0, stream>>>(
        w1t, pw_bf, nullptr, w_efft, 2048, 256, 512, 16, 2, 2);
    beff_kernel<<<dim3(2048 / 256, 512 / 64), 256, 0, stream>>>(proj_b, w1, b_eff, 2048);

    auto gemm_grid = [&](int NB) { return 8 * XT * NB; };

    // --- layer 1 (H=4, concat, ELU):  h = x @ W_eff + b_eff ---
    gemm_bf16_kernel<<<gemm_grid(16), 256, 0, stream>>>(
        x_bf, w_efft, b_eff, h_bf, n, 2048, 256, MB, 16, XT);
    esed_kernel<<<n, 4 * 64, 0, stream>>>(h_bf, as1, ad1, es, ed, 4);
    agg_kernel<4, 8, false><<<n, 256, 0, stream>>>(h_bf, es, ed, csr, off, b1,
                                                   nullptr, act_bf, 1);

    // --- layer 2 (H=4, concat, ELU) ---
    gemm_bf16_kernel<<<gemm_grid(16), 256, 0, stream>>>(
        act_bf, w2t, nullptr, h_bf, n, 2048, 2048, MB, 16, XT);
    esed_kernel<<<n, 4 * 64, 0, stream>>>(h_bf, as2, ad2, es, ed, 4);
    agg_kernel<4, 8, false><<<n, 256, 0, stream>>>(h_bf, es, ed, csr, off, b2,
                                                   nullptr, act_bf, 1);

    // --- layer 3 (H=2, mean+bias fused, no ELU) ---
    gemm_bf16_kernel<<<gemm_grid(8), 256, 0, stream>>>(
        act_bf, w3t, nullptr, h_bf, n, 1024, 2048, MB, 8, XT);
    esed_kernel<<<n, 2 * 64, 0, stream>>>(h_bf, as3, ad3, es, ed, 2);
    agg_kernel<2, 4, true><<<n, 256, 0, stream>>>(h_bf, es, ed, csr, off, b3,
                                                  (float*)d_out, nullptr, 0);
}